// Round 7
// baseline (306.184 us; speedup 1.0000x reference)
//
#include <hip/hip_runtime.h>
#include <hip/hip_bf16.h>

// Problem constants (from reference setup_inputs)
static constexpr int NN  = 100000;   // nodes
static constexpr int NE  = 1600000;  // edges
static constexpr int FIN = 128;      // input features
static constexpr int HD  = 64;       // hidden

// Two-level counting sort parameters
static constexpr int NB    = 256;    // coarse buckets
static constexpr int NPB   = 392;    // nodes per bucket (256*392 = 100352 >= NN)
static constexpr int NSLOT = NB * NPB;  // 100352 ranked slots
static constexpr int EPB   = NE / NB;   // 6250 edges per hist/binfill block
static constexpr unsigned long long DIV392_MAGIC = 43826197ULL;  // floor(c/392) = (c*M)>>34

// Feature slicing for XCD-local gathers: 4 slices x 16 features (32 B rows).
// slice = blockIdx.x & 3 pins each 3.2 MB slice to 2 XCDs' L2s.
static constexpr int NSL = 4;

// Aggregation block geometry: 64 ranked slots/block, 4 threads/slot
// (2 edge slots x 2 feature halves). Degree-ranked waves -> uniform loop counts.
static constexpr int AGN  = 64;
static constexpr int ACAP = 3072;    // staged-index capacity (64 x maxdeg~45 fits)

typedef __attribute__((ext_vector_type(8))) short bf16x8;
typedef __attribute__((ext_vector_type(4))) float f32x4;

__device__ __forceinline__ float bf2f(unsigned short u) {
    return __uint_as_float(((unsigned int)u) << 16);
}
__device__ __forceinline__ unsigned short f2bf(float f) {
    __hip_bfloat16 hb = __float2bfloat16(f);
    return *(unsigned short*)&hb;
}
__device__ __forceinline__ int bucket_of(int c) {
    return (int)(((unsigned long long)(unsigned int)c * DIV392_MAGIC) >> 34);
}

__device__ __forceinline__ float load_in(const void* p, size_t i, int isbf) {
    return isbf ? bf2f(((const unsigned short*)p)[i]) : ((const float*)p)[i];
}

// ---------- Phase A: histogram over 256 coarse buckets, 4 per-wave LDS copies.
// Block 0 additionally runs the dtype-detect.
__global__ __launch_bounds__(256) void k_hist(const int* __restrict__ col, int* __restrict__ hist,
                                              const unsigned short* __restrict__ xu,
                                              int* __restrict__ flag) {
    __shared__ int h[4][NB];
    int t = threadIdx.x, w = t >> 6;
#pragma unroll
    for (int r = 0; r < 4; ++r) h[r][t] = 0;
    __syncthreads();
    int base = blockIdx.x * EPB;
    for (int e = base + t; e < base + EPB; e += 256)
        atomicAdd(&h[w][bucket_of(col[e])], 1);
    __syncthreads();
    hist[t * NB + blockIdx.x] = h[0][t] + h[1][t] + h[2][t] + h[3][t];   // hist[bucket][block]
    if (blockIdx.x == 0) {
        __syncthreads();
        int cnt = 0;
        for (int k = t; k < 4096; k += 256) {
            unsigned short u = xu[2 * k];
            int ex = (u >> 7) & 0xFF;
            cnt += (ex >= 110 && ex <= 135) ? 1 : 0;
        }
        h[0][t] = cnt;
        __syncthreads();
        for (int off = 128; off > 0; off >>= 1) {
            if (t < off) h[0][t] += h[0][t + off];
            __syncthreads();
        }
        if (t == 0) flag[0] = (h[0][0] >= 2048) ? 1 : 0;
    }
}

// ---------- Phase B: exclusive scan of 65536 ints (chunk part; bsums kept RAW —
// consumers fold the 64-entry bsums scan locally).
__global__ __launch_bounds__(256) void k_gscan1(int* __restrict__ a, int* __restrict__ bsums) {
    __shared__ int sd[256];
    int t = threadIdx.x;
    int base = blockIdx.x * 1024 + t * 4;
    int v0 = a[base], v1 = a[base + 1], v2 = a[base + 2], v3 = a[base + 3];
    int tsum = v0 + v1 + v2 + v3;
    sd[t] = tsum;
    __syncthreads();
    for (int off = 1; off < 256; off <<= 1) {
        int tmp = (t >= off) ? sd[t - off] : 0;
        __syncthreads();
        sd[t] += tmp;
        __syncthreads();
    }
    int run = sd[t] - tsum;
    a[base] = run; run += v0;
    a[base + 1] = run; run += v1;
    a[base + 2] = run; run += v2;
    a[base + 3] = run;
    if (t == 255) bsums[blockIdx.x] = sd[t];
}

// In-block exclusive scan of the 64 raw bsums into sb[]. All 256 threads hit barriers.
__device__ __forceinline__ void scan_bsums(const int* __restrict__ bsumsRaw, int* sb) {
    int t = threadIdx.x;
    int myv = 0;
    if (t < 64) { myv = bsumsRaw[t]; sb[t] = myv; }
    __syncthreads();
    for (int off = 1; off < 64; off <<= 1) {
        int v = (t < 64 && t >= off) ? sb[t - off] : 0;
        __syncthreads();
        if (t < 64) sb[t] += v;
        __syncthreads();
    }
    if (t < 64) sb[t] -= myv;   // exclusive
    __syncthreads();
}

// ---------- Phase C: scatter packed (src | dst_local<<17) into bucket-grouped order.
// Scatter targets stay within ~25 KB bucket windows -> L2-resident, no write blowup.
__global__ __launch_bounds__(256) void k_binfill(const int* __restrict__ row, const int* __restrict__ col,
                                                 const int* __restrict__ histS,
                                                 const int* __restrict__ bsumsRaw,
                                                 int* __restrict__ csr_tmp) {
    __shared__ int cur[NB];
    __shared__ int sb[64];
    int t = threadIdx.x;
    scan_bsums(bsumsRaw, sb);
    cur[t] = histS[t * NB + blockIdx.x] + sb[t >> 2];
    __syncthreads();
    int base = blockIdx.x * EPB;
    for (int e = base + t; e < base + EPB; e += 256) {
        int r = row[e], c = col[e];
        int b = bucket_of(c);
        int p = atomicAdd(&cur[b], 1);
        csr_tmp[p] = r | ((c - b * NPB) << 17);   // r < 2^17, c_local < 392 < 2^9
    }
}

// ---------- Phase D: per-bucket DEGREE-RANKED counting sort.
// Emits perm[slot] (rank->node), rankedEnd[slot] (contiguous segment ends in rank
// order), csr_src grouped by ranked segments, and dinv. Degree-uniform waves in the
// aggregation remove tail divergence (wave time = max deg of its 16 nodes).
__global__ __launch_bounds__(256) void k_bsort(const int* __restrict__ csr_tmp,
                                               const int* __restrict__ histS,
                                               const int* __restrict__ bsumsRaw,
                                               int* __restrict__ csr_src,
                                               int* __restrict__ rankedEnd,
                                               int* __restrict__ perm,
                                               float* __restrict__ dinv) {
    __shared__ int h1[512];    // c_local hist -> (reused) per-bin slot cursors
    __shared__ int h2[512];    // degree hist -> exclusive scan = slot base per bin
    __shared__ int h3[512];    // per-bin edge sums -> exclusive scan = edge base per bin
    __shared__ int segS[512];  // per-local-node segment cursor
    __shared__ int sb[64];
    __shared__ int bigCur;     // edge cursor for clamp bin 511 (deg>=511: ~impossible)
    int t = threadIdx.x;
    int k = blockIdx.x;
    h1[t] = 0; h1[t + 256] = 0;
    h2[t] = 0; h2[t + 256] = 0;
    h3[t] = 0; h3[t + 256] = 0;
    scan_bsums(bsumsRaw, sb);    // internal barriers make the zeroing visible
    int S = histS[k * NB] + sb[k >> 2];
    int E = (k < NB - 1) ? (histS[(k + 1) * NB] + sb[(k + 1) >> 2]) : NE;
    int nbase = k * NPB;
    int validCnt = NN - nbase; if (validCnt > NPB) validCnt = NPB; if (validCnt < 0) validCnt = 0;
    // 1. per-dst hist
    for (int e = S + t; e < E; e += 256)
        atomicAdd(&h1[csr_tmp[e] >> 17], 1);
    __syncthreads();
    int rc0 = h1[t], rc1 = h1[t + 256];
    __syncthreads();                 // all degrees read before h1 reuse
    h1[t] = 0; h1[t + 256] = 0;      // h1 becomes per-bin slot cursors
    bool v0 = (t < validCnt);
    bool v1 = (t + 256 < validCnt);
    int b0 = (rc0 < 511) ? rc0 : 511;
    int b1 = (rc1 < 511) ? rc1 : 511;
    // 2. degree hist + per-bin edge totals (h3[b] = sum of degs in bin, exact)
    if (v0) { atomicAdd(&h2[b0], 1); atomicAdd(&h3[b0], rc0); }
    if (v1) { atomicAdd(&h2[b1], 1); atomicAdd(&h3[b1], rc1); }
    __syncthreads();
    // 3. Blelloch exclusive scans of h2 (slot bases) and h3 (edge bases)
    for (int d = 1; d < 512; d <<= 1) {
        int idx = (t + 1) * (d << 1) - 1;
        if (idx < 512) { h2[idx] += h2[idx - d]; h3[idx] += h3[idx - d]; }
        __syncthreads();
    }
    if (t == 0) { h2[511] = 0; h3[511] = 0; }
    __syncthreads();
    for (int d = 256; d >= 1; d >>= 1) {
        int idx = (t + 1) * (d << 1) - 1;
        if (idx < 512) {
            int a2 = h2[idx - d]; h2[idx - d] = h2[idx]; h2[idx] += a2;
            int a3 = h3[idx - d]; h3[idx - d] = h3[idx]; h3[idx] += a3;
        }
        __syncthreads();
    }
    if (t == 0) bigCur = h3[511];
    __syncthreads();
    // 4. assign ranked slots + contiguous edge segments
    if (v0) {
        int n = nbase + t;
        int sr = atomicAdd(&h1[b0], 1);
        int slot = h2[b0] + sr;
        int segOff = (b0 < 511) ? (h3[b0] + sr * b0) : atomicAdd(&bigCur, rc0);
        perm[nbase + slot] = n;
        rankedEnd[nbase + slot] = S + segOff + rc0;
        segS[t] = S + segOff;
        dinv[n] = rsqrtf((float)(rc0 + 1));
    }
    if (v1) {
        int n = nbase + t + 256;
        int sr = atomicAdd(&h1[b1], 1);
        int slot = h2[b1] + sr;
        int segOff = (b1 < 511) ? (h3[b1] + sr * b1) : atomicAdd(&bigCur, rc1);
        perm[nbase + slot] = n;
        rankedEnd[nbase + slot] = S + segOff + rc1;
        segS[t + 256] = S + segOff;
        dinv[n] = rsqrtf((float)(rc1 + 1));
    }
    // invalid tail slots: empty ranges, keep rankedEnd contiguous across buckets
    for (int s = validCnt + t; s < NPB; s += 256) {
        perm[nbase + s] = -1;
        rankedEnd[nbase + s] = E;
    }
    __syncthreads();
    // 5. scatter edges into ranked segments
    for (int e = S + t; e < E; e += 256) {
        int u = csr_tmp[e];
        int p = atomicAdd(&segS[u >> 17], 1);
        csr_src[p] = u & 0x1FFFF;
    }
}

// ---------- MFMA node GEMM: writes slice-major T4[slice][n][16] (bf16)
//            = dinv[n] * (X[NN][K] @ W[K][64]) with slice = feature>>4.
// Frag layouts (HW-verified): A[m=lane&15][k=quad*8+j], B[k=quad*8+j][n=lane&15],
// D[row=quad*4+r][col=lane&15].
template <int K, bool XDUAL>
__global__ __launch_bounds__(256) void k_gemm_mfma(const void* __restrict__ X,
                                                   const void* __restrict__ W,
                                                   const float* __restrict__ dinv,
                                                   unsigned short* __restrict__ T4,
                                                   const int* __restrict__ flag) {
    constexpr int KT = K / 32;
    __shared__ unsigned short Bs[KT * 4 * 64 * 8];  // [kt][nt][lane][8], frag-layout
    int isbf = flag[0];
    for (int tup = threadIdx.x; tup < KT * 4 * 64; tup += 256) {
        int l  = tup & 63;
        int nt = (tup >> 6) & 3;
        int kt = tup >> 8;
        int n  = nt * 16 + (l & 15);
        int kb = kt * 32 + (l >> 4) * 8;
        unsigned short tmp[8];
#pragma unroll
        for (int j = 0; j < 8; ++j) tmp[j] = f2bf(load_in(W, (size_t)(kb + j) * HD + n, isbf));
        *((uint4*)&Bs[(size_t)tup * 8]) = *((const uint4*)tmp);
    }
    __syncthreads();
    int wave = threadIdx.x >> 6, lane = threadIdx.x & 63;
    int quad = lane >> 4, m = lane & 15;
    int row0 = blockIdx.x * 64 + wave * 16;
    int row  = row0 + m;
    int rowc = (row < NN) ? row : (NN - 1);
    bool xf32 = XDUAL && (isbf == 0);
    const char* xrow = (const char*)X + (size_t)rowc * K * (xf32 ? 4 : 2);
    f32x4 acc[4];
#pragma unroll
    for (int nt = 0; nt < 4; ++nt) acc[nt] = (f32x4){0.f, 0.f, 0.f, 0.f};
#pragma unroll
    for (int kt = 0; kt < KT; ++kt) {
        bf16x8 a;
        if (!xf32) {
            a = *((const bf16x8*)(xrow + (size_t)(kt * 32 + quad * 8) * 2));
        } else {
            const float4* fp = (const float4*)(xrow + (size_t)(kt * 32 + quad * 8) * 4);
            float4 u0 = fp[0], u1 = fp[1];
            unsigned short tmp[8] = {f2bf(u0.x), f2bf(u0.y), f2bf(u0.z), f2bf(u0.w),
                                     f2bf(u1.x), f2bf(u1.y), f2bf(u1.z), f2bf(u1.w)};
            a = *((const bf16x8*)tmp);
        }
#pragma unroll
        for (int nt = 0; nt < 4; ++nt) {
            bf16x8 b = *((const bf16x8*)&Bs[(size_t)((kt * 4 + nt) * 64 + lane) * 8]);
            acc[nt] = __builtin_amdgcn_mfma_f32_16x16x32_bf16(a, b, acc[nt], 0, 0, 0);
        }
    }
#pragma unroll
    for (int r = 0; r < 4; ++r) {
        int orow = row0 + quad * 4 + r;
        if (orow < NN) {
            float sc = dinv[orow];
#pragma unroll
            for (int nt = 0; nt < 4; ++nt)
                T4[((size_t)nt * NN + orow) * 16 + m] = f2bf(acc[nt][r] * sc);
        }
    }
}

// ---------- XCD-sliced aggregation over degree-ranked slots:
// block = (64 ranked slots) x (feature slice); 4 threads/slot = 2 edge slots x 2
// halves. Ranked segments are contiguous -> coalesced LDS staging; degree-uniform
// waves -> no tail divergence. Writes H4[slice][perm[slot]].
__global__ __launch_bounds__(256) void k_agg4(const unsigned short* __restrict__ T4,
                                              const int* __restrict__ rankedEnd,
                                              const int* __restrict__ perm,
                                              const int* __restrict__ csr_src,
                                              const float* __restrict__ dinv,
                                              const void* __restrict__ bias,
                                              const int* __restrict__ flag,
                                              unsigned short* __restrict__ H4) {
    __shared__ int sIdx[ACAP];
    __shared__ int sEnd[AGN + 1];
    __shared__ int sPerm[AGN];
    int isbf = flag[0];
    int slice = blockIdx.x & 3;
    int grp   = blockIdx.x >> 2;
    int i0 = grp * AGN;          // slot base; grid covers NSLOT exactly
    int t = threadIdx.x;
    if (t <= AGN) {
        int g = i0 + t - 1;
        sEnd[t] = (g < 0) ? 0 : rankedEnd[g];
    }
    if (t < AGN) sPerm[t] = perm[i0 + t];
    __syncthreads();
    int base  = sEnd[0];
    int total = sEnd[AGN] - base;
    bool fast = (total <= ACAP);
    if (fast)
        for (int k = t; k < total; k += 256) sIdx[k] = csr_src[base + k];
    __syncthreads();
    int li   = t >> 2;           // slot within block (0..63)
    int slot = (t >> 1) & 1;     // edge slot (0..1), lane bit 1
    int fl   = (t & 1) * 8;      // feature half within slice (0 or 8)
    int i    = sPerm[li];        // node id (-1 = invalid slot)
    const unsigned short* Ts = T4 + (size_t)slice * NN * 16;
    union U { uint4 u; unsigned short s[8]; };
    float a[8];
#pragma unroll
    for (int j = 0; j < 8; ++j) a[j] = 0.f;
    if (i >= 0) {
        int beg = sEnd[li] - base;
        int end = sEnd[li + 1] - base;
        int k = beg + slot;
        if (fast) {
            for (; k + 6 < end; k += 8) {   // 4 independent gathers in flight
                int s0 = sIdx[k], s1 = sIdx[k + 2], s2 = sIdx[k + 4], s3 = sIdx[k + 6];
                U t0, t1, t2, t3;
                t0.u = *((const uint4*)(Ts + (size_t)s0 * 16 + fl));
                t1.u = *((const uint4*)(Ts + (size_t)s1 * 16 + fl));
                t2.u = *((const uint4*)(Ts + (size_t)s2 * 16 + fl));
                t3.u = *((const uint4*)(Ts + (size_t)s3 * 16 + fl));
#pragma unroll
                for (int j = 0; j < 8; ++j)
                    a[j] += bf2f(t0.s[j]) + bf2f(t1.s[j]) + bf2f(t2.s[j]) + bf2f(t3.s[j]);
            }
            for (; k < end; k += 2) {
                int s = sIdx[k];
                U tv; tv.u = *((const uint4*)(Ts + (size_t)s * 16 + fl));
#pragma unroll
                for (int j = 0; j < 8; ++j) a[j] += bf2f(tv.s[j]);
            }
        } else {   // overflow fallback: read indices straight from global
            for (; k + 6 < end; k += 8) {
                int s0 = csr_src[base + k],     s1 = csr_src[base + k + 2];
                int s2 = csr_src[base + k + 4], s3 = csr_src[base + k + 6];
                U t0, t1, t2, t3;
                t0.u = *((const uint4*)(Ts + (size_t)s0 * 16 + fl));
                t1.u = *((const uint4*)(Ts + (size_t)s1 * 16 + fl));
                t2.u = *((const uint4*)(Ts + (size_t)s2 * 16 + fl));
                t3.u = *((const uint4*)(Ts + (size_t)s3 * 16 + fl));
#pragma unroll
                for (int j = 0; j < 8; ++j)
                    a[j] += bf2f(t0.s[j]) + bf2f(t1.s[j]) + bf2f(t2.s[j]) + bf2f(t3.s[j]);
            }
            for (; k < end; k += 2) {
                int s = csr_src[base + k];
                U tv; tv.u = *((const uint4*)(Ts + (size_t)s * 16 + fl));
#pragma unroll
                for (int j = 0; j < 8; ++j) a[j] += bf2f(tv.s[j]);
            }
        }
    }
    // combine the 2 edge slots (lanes differing in bit 1 — same wave)
#pragma unroll
    for (int j = 0; j < 8; ++j) a[j] += __shfl_xor(a[j], 2, 64);
    if (i >= 0 && slot == 0) {
        float di = dinv[i];
        U sf; sf.u = *((const uint4*)(Ts + (size_t)i * 16 + fl));
        U o;
#pragma unroll
        for (int j = 0; j < 8; ++j) {
            float v = a[j] + bf2f(sf.s[j]);
            float b = load_in(bias, (size_t)(slice * 16 + fl + j), isbf);
            o.s[j] = f2bf(fmaxf(fmaf(di, v, b), 0.f));
        }
        *((uint4*)(H4 + ((size_t)slice * NN + i) * 16 + fl)) = o.u;
    }
}

// ---------- hidden GEMM: Tb4 = dinv * (H4 @ W), slice-major in and out. K = 64.
__global__ __launch_bounds__(256) void k_gemm_h(const unsigned short* __restrict__ H4,
                                                const void* __restrict__ W,
                                                const float* __restrict__ dinv,
                                                unsigned short* __restrict__ Tb4,
                                                const int* __restrict__ flag) {
    __shared__ unsigned short Bs[2 * 4 * 64 * 8];
    int isbf = flag[0];
    for (int tup = threadIdx.x; tup < 512; tup += 256) {
        int l  = tup & 63;
        int nt = (tup >> 6) & 3;
        int kt = tup >> 8;
        int n  = nt * 16 + (l & 15);
        int kb = kt * 32 + (l >> 4) * 8;
        unsigned short tmp[8];
#pragma unroll
        for (int j = 0; j < 8; ++j) tmp[j] = f2bf(load_in(W, (size_t)(kb + j) * HD + n, isbf));
        *((uint4*)&Bs[(size_t)tup * 8]) = *((const uint4*)tmp);
    }
    __syncthreads();
    int wave = threadIdx.x >> 6, lane = threadIdx.x & 63;
    int quad = lane >> 4, m = lane & 15;
    int row0 = blockIdx.x * 64 + wave * 16;
    int row  = row0 + m;
    int rowc = (row < NN) ? row : (NN - 1);
    f32x4 acc[4];
#pragma unroll
    for (int nt = 0; nt < 4; ++nt) acc[nt] = (f32x4){0.f, 0.f, 0.f, 0.f};
#pragma unroll
    for (int kt = 0; kt < 2; ++kt) {
        int k0 = kt * 32 + quad * 8;
        bf16x8 a = *((const bf16x8*)&H4[((size_t)(k0 >> 4) * NN + rowc) * 16 + (k0 & 15)]);
#pragma unroll
        for (int nt = 0; nt < 4; ++nt) {
            bf16x8 b = *((const bf16x8*)&Bs[(size_t)((kt * 4 + nt) * 64 + lane) * 8]);
            acc[nt] = __builtin_amdgcn_mfma_f32_16x16x32_bf16(a, b, acc[nt], 0, 0, 0);
        }
    }
#pragma unroll
    for (int r = 0; r < 4; ++r) {
        int orow = row0 + quad * 4 + r;
        if (orow < NN) {
            float sc = dinv[orow];
#pragma unroll
            for (int nt = 0; nt < 4; ++nt)
                Tb4[((size_t)nt * NN + orow) * 16 + m] = f2bf(acc[nt][r] * sc);
        }
    }
}

// ---------- edge-projection GEMM from sliced H: P[n][0:8] = H[n]@Wl[0:64] + bl,
// P[n][8:16] = H[n]@Wl[64:128] (packed 16-col B).
__global__ __launch_bounds__(256) void k_pgemm_h(const unsigned short* __restrict__ H4,
                                                 const void* __restrict__ Wl,
                                                 const void* __restrict__ bl,
                                                 unsigned short* __restrict__ P,
                                                 const int* __restrict__ flag) {
    int isbf = flag[0];
    int wave = threadIdx.x >> 6, lane = threadIdx.x & 63;
    int quad = lane >> 4, m = lane & 15;
    bf16x8 bfr[2];
#pragma unroll
    for (int kt = 0; kt < 2; ++kt) {
        unsigned short tmp[8];
#pragma unroll
        for (int j = 0; j < 8; ++j) {
            int kk = kt * 32 + quad * 8 + j;
            float w = (m < 8) ? load_in(Wl, (size_t)kk * 8 + m, isbf)
                              : load_in(Wl, (size_t)(64 + kk) * 8 + (m - 8), isbf);
            tmp[j] = f2bf(w);
        }
        bfr[kt] = *((const bf16x8*)tmp);
    }
    float binit = (m < 8) ? load_in(bl, m, isbf) : 0.f;
    int row0 = blockIdx.x * 64 + wave * 16;
    int row  = row0 + m;
    int rowc = (row < NN) ? row : (NN - 1);
    f32x4 acc = (f32x4){binit, binit, binit, binit};
#pragma unroll
    for (int kt = 0; kt < 2; ++kt) {
        int k0 = kt * 32 + quad * 8;
        bf16x8 a = *((const bf16x8*)&H4[((size_t)(k0 >> 4) * NN + rowc) * 16 + (k0 & 15)]);
        acc = __builtin_amdgcn_mfma_f32_16x16x32_bf16(a, bfr[kt], acc, 0, 0, 0);
    }
#pragma unroll
    for (int r = 0; r < 4; ++r) {
        int orow = row0 + quad * 4 + r;
        if (orow < NN) P[(size_t)orow * 16 + m] = f2bf(acc[r]);
    }
}

// ---------- edge output: out[e] = P[row[e]][0:8] + P[col[e]][8:16]  (bl already in P)
__global__ __launch_bounds__(256) void k_edge_add(const unsigned short* __restrict__ P,
                                                  const int* __restrict__ erow,
                                                  const int* __restrict__ ecol,
                                                  void* __restrict__ out,
                                                  const int* __restrict__ flag) {
    int isbf = flag[0];
    int e = blockIdx.x * 256 + threadIdx.x;   // NE % 256 == 0
    int i = erow[e], j = ecol[e];
    union U { uint4 u; unsigned short s[8]; };
    U a, b;
    a.u = *((const uint4*)(P + (size_t)i * 16));       // P[i][0:8]
    b.u = *((const uint4*)(P + (size_t)j * 16 + 8));   // P[j][8:16]
    float v[8];
#pragma unroll
    for (int o = 0; o < 8; ++o) v[o] = bf2f(a.s[o]) + bf2f(b.s[o]);
    if (isbf) {
        union { unsigned short h[8]; uint4 u; } p;
#pragma unroll
        for (int o = 0; o < 8; ++o) p.h[o] = f2bf(v[o]);
        *((uint4*)((__hip_bfloat16*)out + (size_t)e * 8)) = p.u;
    } else {
        float* op = (float*)out + (size_t)e * 8;
        ((float4*)op)[0] = make_float4(v[0], v[1], v[2], v[3]);
        ((float4*)op)[1] = make_float4(v[4], v[5], v[6], v[7]);
    }
}

extern "C" void kernel_launch(void* const* d_in, const int* in_sizes, int n_in,
                              void* d_out, int out_size, void* d_ws, size_t ws_size,
                              hipStream_t stream) {
    const void* x  = d_in[0];
    const int*  ei = (const int*)d_in[1];
    const void* W1 = d_in[2];
    const void* b1 = d_in[3];
    const void* W2 = d_in[4];
    const void* b2 = d_in[5];
    const void* Wl = d_in[6];
    const void* bl = d_in[7];
    const int* row = ei;
    const int* col = ei + NE;

    char* ws = (char*)d_ws;
    int*   flag    = (int*)ws;    ws += 16;
    int*   hist    = (int*)ws;    ws += (size_t)NB * NB * 4;   // 256 KB, scanned in place
    int*   bsums   = (int*)ws;    ws += 256 * 4;
    int*   rankedEnd = (int*)ws;  ws += (size_t)NSLOT * 4;     // ranked segment ends
    int*   perm    = (int*)ws;    ws += (size_t)NSLOT * 4;     // rank -> node id
    float* dinv    = (float*)ws;  ws += (size_t)NN * 4;
    int*   csr_tmp = (int*)ws;    ws += (size_t)NE * 4;
    int*   csr_src = (int*)ws;    ws += (size_t)NE * 4;
    unsigned short* T4  = (unsigned short*)ws;  ws += (size_t)NN * 64 * 2;  // 12.8 MB, sliced
    unsigned short* H4  = (unsigned short*)ws;  ws += (size_t)NN * 64 * 2;  // 12.8 MB, sliced
    unsigned short* Tb4 = (unsigned short*)ws;  ws += (size_t)NN * 64 * 2;  // 12.8 MB, sliced
    unsigned short* P   = (unsigned short*)ws;                              // 3.2 MB

    int gE   = (NE + 255) / 256;
    int gN64 = (NN + 63) / 64;          // mfma gemms: 64 rows/block
    int gAgg = (NSLOT / AGN) * NSL;     // agg: (64-slot group) x (feature slice)

    // CSR build: histogram(+detect) -> chunk scan -> bin scatter -> degree-ranked sort
    k_hist   <<<NB, 256, 0, stream>>>(col, hist, (const unsigned short*)x, flag);
    k_gscan1 <<<64, 256, 0, stream>>>(hist, bsums);
    k_binfill<<<NB, 256, 0, stream>>>(row, col, hist, bsums, csr_tmp);
    k_bsort  <<<NB, 256, 0, stream>>>(csr_tmp, hist, bsums, csr_src, rankedEnd, perm, dinv);

    // conv1: T4 = dinv * (x @ W1) sliced; degree-ranked XCD-local agg -> H4
    k_gemm_mfma<FIN, true><<<gN64, 256, 0, stream>>>(x, W1, dinv, T4, flag);
    k_agg4 <<<gAgg, 256, 0, stream>>>(T4, rankedEnd, perm, csr_src, dinv, b1, flag, H4);

    // conv2: Tb4 = dinv * (H4 @ W2) sliced; agg -> H4 reused as h2 (sliced)
    k_gemm_h<<<gN64, 256, 0, stream>>>(H4, W2, dinv, Tb4, flag);
    k_agg4 <<<gAgg, 256, 0, stream>>>(Tb4, rankedEnd, perm, csr_src, dinv, b2, flag, H4);

    // edge head: P = h2 @ Wl (+bl), then gather-add from L2-resident P
    k_pgemm_h<<<gN64, 256, 0, stream>>>(H4, Wl, bl, P, flag);
    k_edge_add<<<gE, 256, 0, stream>>>(P, row, col, d_out, flag);
}

// Round 8
// 291.925 us; speedup vs baseline: 1.0488x; 1.0488x over previous
//
#include <hip/hip_runtime.h>
#include <hip/hip_bf16.h>

// Problem constants (from reference setup_inputs)
static constexpr int NN  = 100000;   // nodes
static constexpr int NE  = 1600000;  // edges
static constexpr int FIN = 128;      // input features
static constexpr int HD  = 64;       // hidden

// Two-level counting sort parameters
static constexpr int NB    = 256;    // coarse buckets
static constexpr int NPB   = 392;    // nodes per bucket (256*392 = 100352 >= NN)
static constexpr int EPB   = NE / NB;   // 6250 edges per hist/binfill block
static constexpr unsigned long long DIV392_MAGIC = 43826197ULL;  // floor(c/392) = (c*M)>>34

// Feature slicing for XCD-local gathers: 4 slices x 16 features (32 B rows).
// Tables stored slice-major: T4[slice][node][16] bf16 -> each slice = 3.2 MB,
// fits one XCD's 4 MB L2. slice = blockIdx.x & 3 pins each slice to 2 XCDs.
static constexpr int NSL = 4;

// Aggregation block geometry: 64 dst nodes/block, 4 threads/node
// (2 edge slots x 2 feature halves). Edge indices staged in LDS.
static constexpr int AGN  = 64;
static constexpr int ACAP = 1536;    // staged-index capacity (mean 1024, 16-sigma safe)

typedef __attribute__((ext_vector_type(8))) short bf16x8;
typedef __attribute__((ext_vector_type(4))) float f32x4;

__device__ __forceinline__ float bf2f(unsigned short u) {
    return __uint_as_float(((unsigned int)u) << 16);
}
__device__ __forceinline__ unsigned short f2bf(float f) {
    __hip_bfloat16 hb = __float2bfloat16(f);
    return *(unsigned short*)&hb;
}
__device__ __forceinline__ int bucket_of(int c) {
    return (int)(((unsigned long long)(unsigned int)c * DIV392_MAGIC) >> 34);
}

__device__ __forceinline__ float load_in(const void* p, size_t i, int isbf) {
    return isbf ? bf2f(((const unsigned short*)p)[i]) : ((const float*)p)[i];
}

// ---------- Phase A: histogram over 256 coarse buckets. 1024 threads/block
// (4 waves/SIMD -> latency hiding on the edge loop). Block 0 runs dtype-detect.
__global__ __launch_bounds__(1024) void k_hist(const int* __restrict__ col, int* __restrict__ hist,
                                               const unsigned short* __restrict__ xu,
                                               int* __restrict__ flag) {
    __shared__ int h[4][NB];
    __shared__ int sd[256];
    int t = threadIdx.x;
    int w4 = (t >> 6) & 3;           // 16 waves -> 4 LDS copies (4 waves each)
    if (t < NB) { h[0][t] = 0; h[1][t] = 0; h[2][t] = 0; h[3][t] = 0; }
    __syncthreads();
    int base = blockIdx.x * EPB;
    for (int e = base + t; e < base + EPB; e += 1024)
        atomicAdd(&h[w4][bucket_of(col[e])], 1);
    __syncthreads();
    if (t < NB)
        hist[t * NB + blockIdx.x] = h[0][t] + h[1][t] + h[2][t] + h[3][t];  // hist[bucket][block]
    if (blockIdx.x == 0) {
        int cnt = 0;
        if (t < 256) {
            for (int k = t; k < 4096; k += 256) {
                unsigned short u = xu[2 * k];
                int ex = (u >> 7) & 0xFF;
                cnt += (ex >= 110 && ex <= 135) ? 1 : 0;
            }
            sd[t] = cnt;
        }
        __syncthreads();
        for (int off = 128; off > 0; off >>= 1) {
            if (t < off) sd[t] += sd[t + off];
            __syncthreads();
        }
        if (t == 0) flag[0] = (sd[0] >= 2048) ? 1 : 0;
    }
}

// ---------- Phase B (fused scan + scatter): each block re-reduces the raw hist
// in-block (1024 threads: thread (q,b) sums quarter q of bucket b's row and the
// prefix below this block), scans bucket totals in LDS, then scatters its edge
// chunk into bucket-grouped csr_tmp via LDS cursors. Block 0 emits bucketBase.
// Removes the separate k_gscan1 dispatch entirely.
__global__ __launch_bounds__(1024) void k_binfill(const int* __restrict__ row, const int* __restrict__ col,
                                                  const int* __restrict__ hist,
                                                  int* __restrict__ csr_tmp,
                                                  int* __restrict__ bucketBase) {
    __shared__ int part[4][NB];
    __shared__ int pref[NB];
    __shared__ int sc[NB];
    __shared__ int cur[NB];
    int t = threadIdx.x;
    int b = t & 255, q = t >> 8;     // 1024 threads = 4 quarters x 256 buckets
    int myb = blockIdx.x;
    int mq = myb >> 6, mr = myb & 63;
    int s = 0, p = 0;
    const int* hrow = hist + b * NB + q * 64;
    for (int j = 0; j < 64; j += 4) {
        int4 v = *((const int4*)&hrow[j]);
        if (q == mq) {
            if (j + 0 < mr) p += v.x;
            if (j + 1 < mr) p += v.y;
            if (j + 2 < mr) p += v.z;
            if (j + 3 < mr) p += v.w;
        }
        s += v.x + v.y + v.z + v.w;
    }
    part[q][b] = s;
    if (q == mq) pref[b] = p;
    __syncthreads();
    int tot = 0;
    if (t < NB) {
        int t0 = part[0][t], t1 = part[1][t], t2 = part[2][t], t3 = part[3][t];
        tot = t0 + t1 + t2 + t3;
        int before = pref[t];
        if (mq > 0) before += t0;
        if (mq > 1) before += t1;
        if (mq > 2) before += t2;
        sc[t] = tot;
        cur[t] = before;
    }
    __syncthreads();
    // Hillis-Steele inclusive scan of bucket totals (t < 256 active)
    for (int off = 1; off < NB; off <<= 1) {
        int v = (t < NB && t >= off) ? sc[t - off] : 0;
        __syncthreads();
        if (t < NB) sc[t] += v;
        __syncthreads();
    }
    if (t < NB) cur[t] += sc[t] - tot;   // bucket global start + my block's offset
    if (myb == 0 && t < NB) {
        bucketBase[t] = sc[t] - tot;
        if (t == 0) bucketBase[NB] = NE;
    }
    __syncthreads();
    int base = myb * EPB;
    for (int e = base + t; e < base + EPB; e += 1024) {
        int r = row[e], c = col[e];
        int bb = bucket_of(c);
        int pos = atomicAdd(&cur[bb], 1);
        csr_tmp[pos] = r | ((c - bb * NPB) << 17);   // r < 2^17, c_local < 392 < 2^9
    }
}

// ---------- Phase C: per-bucket counting sort -> csr_src, start (absolute end
// offsets), dinv. 1024 threads/block for latency hiding on the two edge passes.
__global__ __launch_bounds__(1024) void k_bsort(const int* __restrict__ csr_tmp,
                                                const int* __restrict__ bucketBase,
                                                int* __restrict__ csr_src,
                                                int* __restrict__ start,
                                                float* __restrict__ dinv) {
    __shared__ int cnt[512];
    __shared__ int cur[512];
    int t = threadIdx.x;
    int k = blockIdx.x;
    if (t < 512) cnt[t] = 0;
    __syncthreads();
    int S = bucketBase[k], E = bucketBase[k + 1];
    int nbase = k * NPB;
    for (int e = S + t; e < E; e += 1024)
        atomicAdd(&cnt[csr_tmp[e] >> 17], 1);
    __syncthreads();
    int rc = (t < 512) ? cnt[t] : 0;
    __syncthreads();                 // all degree reads done before in-place scan
    for (int d = 1; d < 512; d <<= 1) {
        int idx = (t + 1) * (d << 1) - 1;
        if (idx < 512) cnt[idx] += cnt[idx - d];
        __syncthreads();
    }
    if (t == 0) cnt[511] = 0;
    __syncthreads();
    for (int d = 256; d >= 1; d >>= 1) {
        int idx = (t + 1) * (d << 1) - 1;
        if (idx < 512) { int tmp = cnt[idx - d]; cnt[idx - d] = cnt[idx]; cnt[idx] += tmp; }
        __syncthreads();
    }
    if (t < NPB) {
        int n = nbase + t;
        if (n < NN) {
            start[n] = S + cnt[t] + rc;
            dinv[n] = rsqrtf((float)(rc + 1));
        }
    }
    if (t < 512) cur[t] = cnt[t];
    __syncthreads();
    for (int e = S + t; e < E; e += 1024) {
        int u = csr_tmp[e];
        int p = atomicAdd(&cur[u >> 17], 1);
        csr_src[S + p] = u & 0x1FFFF;
    }
}

// ---------- MFMA node GEMM: writes slice-major T4[slice][n][16] (bf16)
//            = dinv[n] * (X[NN][K] @ W[K][64]) with slice = feature>>4.
// Frag layouts (HW-verified): A[m=lane&15][k=quad*8+j], B[k=quad*8+j][n=lane&15],
// D[row=quad*4+r][col=lane&15].
template <int K, bool XDUAL>
__global__ __launch_bounds__(256) void k_gemm_mfma(const void* __restrict__ X,
                                                   const void* __restrict__ W,
                                                   const float* __restrict__ dinv,
                                                   unsigned short* __restrict__ T4,
                                                   const int* __restrict__ flag) {
    constexpr int KT = K / 32;
    __shared__ unsigned short Bs[KT * 4 * 64 * 8];  // [kt][nt][lane][8], frag-layout
    int isbf = flag[0];
    for (int tup = threadIdx.x; tup < KT * 4 * 64; tup += 256) {
        int l  = tup & 63;
        int nt = (tup >> 6) & 3;
        int kt = tup >> 8;
        int n  = nt * 16 + (l & 15);
        int kb = kt * 32 + (l >> 4) * 8;
        unsigned short tmp[8];
#pragma unroll
        for (int j = 0; j < 8; ++j) tmp[j] = f2bf(load_in(W, (size_t)(kb + j) * HD + n, isbf));
        *((uint4*)&Bs[(size_t)tup * 8]) = *((const uint4*)tmp);
    }
    __syncthreads();
    int wave = threadIdx.x >> 6, lane = threadIdx.x & 63;
    int quad = lane >> 4, m = lane & 15;
    int row0 = blockIdx.x * 64 + wave * 16;
    int row  = row0 + m;
    int rowc = (row < NN) ? row : (NN - 1);
    bool xf32 = XDUAL && (isbf == 0);
    const char* xrow = (const char*)X + (size_t)rowc * K * (xf32 ? 4 : 2);
    f32x4 acc[4];
#pragma unroll
    for (int nt = 0; nt < 4; ++nt) acc[nt] = (f32x4){0.f, 0.f, 0.f, 0.f};
#pragma unroll
    for (int kt = 0; kt < KT; ++kt) {
        bf16x8 a;
        if (!xf32) {
            a = *((const bf16x8*)(xrow + (size_t)(kt * 32 + quad * 8) * 2));
        } else {
            const float4* fp = (const float4*)(xrow + (size_t)(kt * 32 + quad * 8) * 4);
            float4 u0 = fp[0], u1 = fp[1];
            unsigned short tmp[8] = {f2bf(u0.x), f2bf(u0.y), f2bf(u0.z), f2bf(u0.w),
                                     f2bf(u1.x), f2bf(u1.y), f2bf(u1.z), f2bf(u1.w)};
            a = *((const bf16x8*)tmp);
        }
#pragma unroll
        for (int nt = 0; nt < 4; ++nt) {
            bf16x8 b = *((const bf16x8*)&Bs[(size_t)((kt * 4 + nt) * 64 + lane) * 8]);
            acc[nt] = __builtin_amdgcn_mfma_f32_16x16x32_bf16(a, b, acc[nt], 0, 0, 0);
        }
    }
#pragma unroll
    for (int r = 0; r < 4; ++r) {
        int orow = row0 + quad * 4 + r;
        if (orow < NN) {
            float sc = dinv[orow];
#pragma unroll
            for (int nt = 0; nt < 4; ++nt)
                T4[((size_t)nt * NN + orow) * 16 + m] = f2bf(acc[nt][r] * sc);
        }
    }
}

// ---------- XCD-sliced aggregation, LDS-staged indices (round-4 proven config):
// block = (64 dst nodes) x (feature slice); 4 threads/node = 2 edge slots x 2 halves.
// csr_src range for 64 consecutive nodes is contiguous -> coalesced LDS staging;
// each thread issues 4 independent 16B gathers from the L2-resident slice.
__global__ __launch_bounds__(256) void k_agg4(const unsigned short* __restrict__ T4,
                                              const int* __restrict__ endOff,
                                              const int* __restrict__ csr_src,
                                              const float* __restrict__ dinv,
                                              const void* __restrict__ bias,
                                              const int* __restrict__ flag,
                                              unsigned short* __restrict__ H4) {
    __shared__ int sIdx[ACAP];
    __shared__ int sEnd[AGN + 1];
    int isbf = flag[0];
    int slice = blockIdx.x & 3;
    int grp   = blockIdx.x >> 2;
    int i0 = grp * AGN;
    int t = threadIdx.x;
    if (t <= AGN) {
        int n = i0 + t - 1;
        sEnd[t] = (n < 0) ? 0 : endOff[(n < NN) ? n : (NN - 1)];
    }
    __syncthreads();
    int base  = sEnd[0];
    int total = sEnd[AGN] - base;
    bool fast = (total <= ACAP);
    if (fast)
        for (int k = t; k < total; k += 256) sIdx[k] = csr_src[base + k];
    __syncthreads();
    int li   = t >> 2;           // node within block (0..63)
    int slot = (t >> 1) & 1;     // edge slot (0..1), lane bit 1
    int fl   = (t & 1) * 8;      // feature half within slice (0 or 8)
    int i    = i0 + li;
    const unsigned short* Ts = T4 + (size_t)slice * NN * 16;
    union U { uint4 u; unsigned short s[8]; };
    float a[8];
#pragma unroll
    for (int j = 0; j < 8; ++j) a[j] = 0.f;
    if (i < NN) {
        int beg = sEnd[li] - base;
        int end = sEnd[li + 1] - base;
        int k = beg + slot;
        if (fast) {
            for (; k + 6 < end; k += 8) {   // 4 independent gathers in flight
                int s0 = sIdx[k], s1 = sIdx[k + 2], s2 = sIdx[k + 4], s3 = sIdx[k + 6];
                U t0, t1, t2, t3;
                t0.u = *((const uint4*)(Ts + (size_t)s0 * 16 + fl));
                t1.u = *((const uint4*)(Ts + (size_t)s1 * 16 + fl));
                t2.u = *((const uint4*)(Ts + (size_t)s2 * 16 + fl));
                t3.u = *((const uint4*)(Ts + (size_t)s3 * 16 + fl));
#pragma unroll
                for (int j = 0; j < 8; ++j)
                    a[j] += bf2f(t0.s[j]) + bf2f(t1.s[j]) + bf2f(t2.s[j]) + bf2f(t3.s[j]);
            }
            for (; k < end; k += 2) {
                int s = sIdx[k];
                U tv; tv.u = *((const uint4*)(Ts + (size_t)s * 16 + fl));
#pragma unroll
                for (int j = 0; j < 8; ++j) a[j] += bf2f(tv.s[j]);
            }
        } else {   // astronomically-rare overflow: read indices straight from global
            for (; k + 6 < end; k += 8) {
                int s0 = csr_src[base + k],     s1 = csr_src[base + k + 2];
                int s2 = csr_src[base + k + 4], s3 = csr_src[base + k + 6];
                U t0, t1, t2, t3;
                t0.u = *((const uint4*)(Ts + (size_t)s0 * 16 + fl));
                t1.u = *((const uint4*)(Ts + (size_t)s1 * 16 + fl));
                t2.u = *((const uint4*)(Ts + (size_t)s2 * 16 + fl));
                t3.u = *((const uint4*)(Ts + (size_t)s3 * 16 + fl));
#pragma unroll
                for (int j = 0; j < 8; ++j)
                    a[j] += bf2f(t0.s[j]) + bf2f(t1.s[j]) + bf2f(t2.s[j]) + bf2f(t3.s[j]);
            }
            for (; k < end; k += 2) {
                int s = csr_src[base + k];
                U tv; tv.u = *((const uint4*)(Ts + (size_t)s * 16 + fl));
#pragma unroll
                for (int j = 0; j < 8; ++j) a[j] += bf2f(tv.s[j]);
            }
        }
    }
    // combine the 2 edge slots (lanes differing in bit 1 — same wave)
#pragma unroll
    for (int j = 0; j < 8; ++j) a[j] += __shfl_xor(a[j], 2, 64);
    if (i < NN && slot == 0) {
        float di = dinv[i];
        U sf; sf.u = *((const uint4*)(Ts + (size_t)i * 16 + fl));
        U o;
#pragma unroll
        for (int j = 0; j < 8; ++j) {
            float v = a[j] + bf2f(sf.s[j]);
            float b = load_in(bias, (size_t)(slice * 16 + fl + j), isbf);
            o.s[j] = f2bf(fmaxf(fmaf(di, v, b), 0.f));
        }
        *((uint4*)(H4 + ((size_t)slice * NN + i) * 16 + fl)) = o.u;
    }
}

// ---------- hidden GEMM: Tb4 = dinv * (H4 @ W), slice-major in and out. K = 64.
__global__ __launch_bounds__(256) void k_gemm_h(const unsigned short* __restrict__ H4,
                                                const void* __restrict__ W,
                                                const float* __restrict__ dinv,
                                                unsigned short* __restrict__ Tb4,
                                                const int* __restrict__ flag) {
    __shared__ unsigned short Bs[2 * 4 * 64 * 8];
    int isbf = flag[0];
    for (int tup = threadIdx.x; tup < 512; tup += 256) {
        int l  = tup & 63;
        int nt = (tup >> 6) & 3;
        int kt = tup >> 8;
        int n  = nt * 16 + (l & 15);
        int kb = kt * 32 + (l >> 4) * 8;
        unsigned short tmp[8];
#pragma unroll
        for (int j = 0; j < 8; ++j) tmp[j] = f2bf(load_in(W, (size_t)(kb + j) * HD + n, isbf));
        *((uint4*)&Bs[(size_t)tup * 8]) = *((const uint4*)tmp);
    }
    __syncthreads();
    int wave = threadIdx.x >> 6, lane = threadIdx.x & 63;
    int quad = lane >> 4, m = lane & 15;
    int row0 = blockIdx.x * 64 + wave * 16;
    int row  = row0 + m;
    int rowc = (row < NN) ? row : (NN - 1);
    f32x4 acc[4];
#pragma unroll
    for (int nt = 0; nt < 4; ++nt) acc[nt] = (f32x4){0.f, 0.f, 0.f, 0.f};
#pragma unroll
    for (int kt = 0; kt < 2; ++kt) {
        int k0 = kt * 32 + quad * 8;
        bf16x8 a = *((const bf16x8*)&H4[((size_t)(k0 >> 4) * NN + rowc) * 16 + (k0 & 15)]);
#pragma unroll
        for (int nt = 0; nt < 4; ++nt) {
            bf16x8 b = *((const bf16x8*)&Bs[(size_t)((kt * 4 + nt) * 64 + lane) * 8]);
            acc[nt] = __builtin_amdgcn_mfma_f32_16x16x32_bf16(a, b, acc[nt], 0, 0, 0);
        }
    }
#pragma unroll
    for (int r = 0; r < 4; ++r) {
        int orow = row0 + quad * 4 + r;
        if (orow < NN) {
            float sc = dinv[orow];
#pragma unroll
            for (int nt = 0; nt < 4; ++nt)
                Tb4[((size_t)nt * NN + orow) * 16 + m] = f2bf(acc[nt][r] * sc);
        }
    }
}

// ---------- edge-projection GEMM from sliced H: P[n][0:8] = H[n]@Wl[0:64] + bl,
// P[n][8:16] = H[n]@Wl[64:128] (packed 16-col B).
__global__ __launch_bounds__(256) void k_pgemm_h(const unsigned short* __restrict__ H4,
                                                 const void* __restrict__ Wl,
                                                 const void* __restrict__ bl,
                                                 unsigned short* __restrict__ P,
                                                 const int* __restrict__ flag) {
    int isbf = flag[0];
    int wave = threadIdx.x >> 6, lane = threadIdx.x & 63;
    int quad = lane >> 4, m = lane & 15;
    bf16x8 bfr[2];
#pragma unroll
    for (int kt = 0; kt < 2; ++kt) {
        unsigned short tmp[8];
#pragma unroll
        for (int j = 0; j < 8; ++j) {
            int kk = kt * 32 + quad * 8 + j;
            float w = (m < 8) ? load_in(Wl, (size_t)kk * 8 + m, isbf)
                              : load_in(Wl, (size_t)(64 + kk) * 8 + (m - 8), isbf);
            tmp[j] = f2bf(w);
        }
        bfr[kt] = *((const bf16x8*)tmp);
    }
    float binit = (m < 8) ? load_in(bl, m, isbf) : 0.f;
    int row0 = blockIdx.x * 64 + wave * 16;
    int row  = row0 + m;
    int rowc = (row < NN) ? row : (NN - 1);
    f32x4 acc = (f32x4){binit, binit, binit, binit};
#pragma unroll
    for (int kt = 0; kt < 2; ++kt) {
        int k0 = kt * 32 + quad * 8;
        bf16x8 a = *((const bf16x8*)&H4[((size_t)(k0 >> 4) * NN + rowc) * 16 + (k0 & 15)]);
        acc = __builtin_amdgcn_mfma_f32_16x16x32_bf16(a, bfr[kt], acc, 0, 0, 0);
    }
#pragma unroll
    for (int r = 0; r < 4; ++r) {
        int orow = row0 + quad * 4 + r;
        if (orow < NN) P[(size_t)orow * 16 + m] = f2bf(acc[r]);
    }
}

// ---------- edge output: out[e] = P[row[e]][0:8] + P[col[e]][8:16]  (bl already in P)
__global__ __launch_bounds__(256) void k_edge_add(const unsigned short* __restrict__ P,
                                                  const int* __restrict__ erow,
                                                  const int* __restrict__ ecol,
                                                  void* __restrict__ out,
                                                  const int* __restrict__ flag) {
    int isbf = flag[0];
    int e = blockIdx.x * 256 + threadIdx.x;   // NE % 256 == 0
    int i = erow[e], j = ecol[e];
    union U { uint4 u; unsigned short s[8]; };
    U a, b;
    a.u = *((const uint4*)(P + (size_t)i * 16));       // P[i][0:8]
    b.u = *((const uint4*)(P + (size_t)j * 16 + 8));   // P[j][8:16]
    float v[8];
#pragma unroll
    for (int o = 0; o < 8; ++o) v[o] = bf2f(a.s[o]) + bf2f(b.s[o]);
    if (isbf) {
        union { unsigned short h[8]; uint4 u; } p;
#pragma unroll
        for (int o = 0; o < 8; ++o) p.h[o] = f2bf(v[o]);
        *((uint4*)((__hip_bfloat16*)out + (size_t)e * 8)) = p.u;
    } else {
        float* op = (float*)out + (size_t)e * 8;
        ((float4*)op)[0] = make_float4(v[0], v[1], v[2], v[3]);
        ((float4*)op)[1] = make_float4(v[4], v[5], v[6], v[7]);
    }
}

extern "C" void kernel_launch(void* const* d_in, const int* in_sizes, int n_in,
                              void* d_out, int out_size, void* d_ws, size_t ws_size,
                              hipStream_t stream) {
    const void* x  = d_in[0];
    const int*  ei = (const int*)d_in[1];
    const void* W1 = d_in[2];
    const void* b1 = d_in[3];
    const void* W2 = d_in[4];
    const void* b2 = d_in[5];
    const void* Wl = d_in[6];
    const void* bl = d_in[7];
    const int* row = ei;
    const int* col = ei + NE;

    char* ws = (char*)d_ws;
    int*   flag       = (int*)ws;    ws += 16;
    int*   hist       = (int*)ws;    ws += (size_t)NB * NB * 4;   // 256 KB raw hist
    int*   bucketBase = (int*)ws;    ws += (NB + 1) * 4;          // scanned bucket starts
    int*   start      = (int*)ws;    ws += (size_t)NN * 4;        // absolute end offsets
    float* dinv       = (float*)ws;  ws += (size_t)NN * 4;
    int*   csr_tmp    = (int*)ws;    ws += (size_t)NE * 4;
    int*   csr_src    = (int*)ws;    ws += (size_t)NE * 4;
    unsigned short* T4  = (unsigned short*)ws;  ws += (size_t)NN * 64 * 2;  // 12.8 MB, sliced
    unsigned short* H4  = (unsigned short*)ws;  ws += (size_t)NN * 64 * 2;  // 12.8 MB, sliced
    unsigned short* Tb4 = (unsigned short*)ws;  ws += (size_t)NN * 64 * 2;  // 12.8 MB, sliced
    unsigned short* P   = (unsigned short*)ws;                              // 3.2 MB

    int gE   = (NE + 255) / 256;
    int gN64 = (NN + 63) / 64;                  // mfma gemms: 64 rows/block
    int gAgg = ((NN + AGN - 1) / AGN) * NSL;    // agg: (64-node group) x (feature slice)

    // CSR build (3 dispatches, 1024-thread blocks):
    // histogram(+detect) -> fused scan+bin scatter -> per-bucket counting sort
    k_hist   <<<NB, 1024, 0, stream>>>(col, hist, (const unsigned short*)x, flag);
    k_binfill<<<NB, 1024, 0, stream>>>(row, col, hist, csr_tmp, bucketBase);
    k_bsort  <<<NB, 1024, 0, stream>>>(csr_tmp, bucketBase, csr_src, start, dinv);

    // conv1: T4 = dinv * (x @ W1) sliced; XCD-local agg -> H4 = relu-hidden (sliced)
    k_gemm_mfma<FIN, true><<<gN64, 256, 0, stream>>>(x, W1, dinv, T4, flag);
    k_agg4 <<<gAgg, 256, 0, stream>>>(T4, start, csr_src, dinv, b1, flag, H4);

    // conv2: Tb4 = dinv * (H4 @ W2) sliced; agg -> H4 reused as h2 (sliced)
    k_gemm_h<<<gN64, 256, 0, stream>>>(H4, W2, dinv, Tb4, flag);
    k_agg4 <<<gAgg, 256, 0, stream>>>(Tb4, start, csr_src, dinv, b2, flag, H4);

    // edge head: P = h2 @ Wl (+bl), then gather-add from L2-resident P
    k_pgemm_h<<<gN64, 256, 0, stream>>>(H4, Wl, bl, P, flag);
    k_edge_add<<<gE, 256, 0, stream>>>(P, row, col, d_out, flag);
}